// Round 7
// baseline (352.194 us; speedup 1.0000x reference)
//
#include <hip/hip_runtime.h>

#define B_ 8
#define K_ 100000
#define NODES (B_ * K_)
#define C_ 16
#define O_ 16
#define H_ 512
#define W_ 512
#define TSX 32
#define TSY 16
#define NTX (W_ / TSX)          // 16 tile cols
#define NTY (H_ / TSY)          // 32 tile rows
#define NBKT (B_ * NTX * NTY)   // 4096 buckets
#define CAP 512                 // slots/bucket (lambda≈234 incl halo, >18 sigma)
#define EX (TSX + 2)            // 34
#define EY (TSY + 2)            // 18
#define PLANE (EX * EY)         // 612

// proj||bin split: EXACTLY 2048 blocks of 256 thr = 8 blocks/CU x 256 CU
// -> all co-resident (round-3's 2688-block version overflowed capacity and
// serialized; this is the fix). Bin latency hides under proj's BW stream.
#define PROJ_BLKS 1536
#define BIN_BLKS 512
#define TOTAL_BLKS (PROJ_BLKS + BIN_BLKS)         // 2048

// Padded cursors: one 64B line per bucket (atomic same-line RMW spread)
#define CURP 16                                   // ints per cursor (64 B)
#define CUR_BYTES (NBKT * CURP * 4)               // 262144
#define IDS_OFF CUR_BYTES
#define P_OFF (IDS_OFF + NBKT * CAP * 4)          // 262144 + 8388608
#define WS_NEED_PRE ((size_t)P_OFF + (size_t)NODES * O_ * 4)  // ~59.9 MB

__device__ __forceinline__ float bf_lo(unsigned int u) {
    union { unsigned int i; float f; } v; v.i = u << 16; return v.f;
}
__device__ __forceinline__ float bf_hi(unsigned int u) {
    union { unsigned int i; float f; } v; v.i = u & 0xffff0000u; return v.f;
}
__device__ __forceinline__ unsigned short f2bf(float f) {
    union { float f; unsigned int u; } v; v.f = f;
    unsigned int u = v.u;
    u += 0x7fffu + ((u >> 16) & 1u);   // round-to-nearest-even
    return (unsigned short)(u >> 16);
}

// Barrier-free dtype probe: bf16 xy pairs always decode (low half) into
// [0,512]; fp32 low halves are random mantissa -> P(all 256 pass)≈1e-146.
__device__ __forceinline__ int probe_fp32_ballot(const unsigned int* xy) {
    const int lane = threadIdx.x & 63;
    int bad = 0;
    #pragma unroll
    for (int k = 0; k < 4; ++k) {
        float lo = bf_lo(xy[lane + (k << 6)]);
        bad |= !(lo >= 0.0f && lo <= 512.0f);
    }
    return __ballot(bad) != 0ull;
}

__device__ __forceinline__ void decode_xy(const void* xy, int fp32, int n,
                                          int& xs, int& ys)
{
    float x, y;
    if (fp32) { float2 p = ((const float2*)xy)[n]; x = p.x; y = p.y; }
    else { unsigned int u = ((const unsigned int*)xy)[n]; x = bf_lo(u); y = bf_hi(u); }
    xs = min(max((int)rintf(x), 0), W_ - 1);   // rintf == round-half-even == jnp.round
    ys = min(max((int)rintf(y), 0), H_ - 1);
}

__device__ __forceinline__ void load_feat16(const void* feat, size_t n, int fp32,
                                            float* f)
{
    if (fp32) {
        const float4* ff = (const float4*)feat + n * 4;
        float4 a = ff[0], b2 = ff[1], c = ff[2], d = ff[3];
        f[0]=a.x; f[1]=a.y; f[2]=a.z; f[3]=a.w;
        f[4]=b2.x; f[5]=b2.y; f[6]=b2.z; f[7]=b2.w;
        f[8]=c.x; f[9]=c.y; f[10]=c.z; f[11]=c.w;
        f[12]=d.x; f[13]=d.y; f[14]=d.z; f[15]=d.w;
    } else {
        const uint4* ff = (const uint4*)feat + n * 2;
        uint4 A = ff[0], Bv = ff[1];
        f[0]=bf_lo(A.x);  f[1]=bf_hi(A.x);  f[2]=bf_lo(A.y);  f[3]=bf_hi(A.y);
        f[4]=bf_lo(A.z);  f[5]=bf_hi(A.z);  f[6]=bf_lo(A.w);  f[7]=bf_hi(A.w);
        f[8]=bf_lo(Bv.x); f[9]=bf_hi(Bv.x); f[10]=bf_lo(Bv.y); f[11]=bf_hi(Bv.y);
        f[12]=bf_lo(Bv.z); f[13]=bf_hi(Bv.z); f[14]=bf_lo(Bv.w); f[15]=bf_hi(Bv.w);
    }
}

__device__ __forceinline__ void load_weights_lds(float* wl, int fp32,
                                                 const void* w_obj,
                                                 const void* w_prior,
                                                 int tid, int nthreads)
{
    for (int i = tid; i < 2 * O_ * C_; i += nthreads) {
        if (fp32) {
            wl[i] = (i < O_ * C_) ? ((const float*)w_obj)[i]
                                  : ((const float*)w_prior)[i - O_ * C_];
        } else {
            unsigned short raw = (i < O_ * C_)
                ? ((const unsigned short*)w_obj)[i]
                : ((const unsigned short*)w_prior)[i - O_ * C_];
            union { unsigned int u; float f; } v; v.u = ((unsigned int)raw) << 16;
            wl[i] = v.f;
        }
    }
}

// ---------------------------------------------------------------------------
// Pass 1 (proj || bin, co-resident):
//  - blocks [0, 1536): streaming projection feat -> p[n][16], grid-stride,
//    coalesced 64B in / 64B out, zero atomics. BW-bound (~17 us of traffic).
//  - blocks [1536, 2048): binning. Reads only xy+types (6.4 MB), one
//    returning atomicAdd per visit on a padded 64B-line cursor, writes a 4B
//    packed id. ~7 independent visits/thread (MLP); latency hides under proj.
// __launch_bounds__(256,8): 8 waves/SIMD -> caps VGPR at 64 so all 2048
// blocks truly co-reside (round-2's identical proj code compiled to 64).
// ---------------------------------------------------------------------------
template<bool PRE>
__global__ __launch_bounds__(256, 8) void proj_bin(
    const void* __restrict__ feat, const void* __restrict__ xy,
    const int* __restrict__ types,
    const void* __restrict__ w_obj, const void* __restrict__ w_prior,
    int* __restrict__ cursor, int* __restrict__ ids, float* __restrict__ p)
{
    const int tid = threadIdx.x;
    const int blk = blockIdx.x;
    const int fp32 = probe_fp32_ballot((const unsigned int*)xy);

    if (blk < PROJ_BLKS) {
        if constexpr (!PRE) return;        // no p-buffer: proj role is a no-op
        __shared__ float wl[2 * O_ * C_];
        load_weights_lds(wl, fp32, w_obj, w_prior, tid, 256);
        __syncthreads();

        for (int n = blk * 256 + tid; n < NODES; n += PROJ_BLKS * 256) {
            const int t = (types[n] != 0);
            float f[16];
            load_feat16(feat, (size_t)n, fp32, f);
            const float* wrow = &wl[t * O_ * C_];
            float pv[16];
            #pragma unroll
            for (int o = 0; o < O_; ++o) {
                float acc = 0.f;
                #pragma unroll
                for (int c = 0; c < C_; ++c) acc = fmaf(wrow[o * C_ + c], f[c], acc);
                pv[o] = acc;
            }
            float4* pout = (float4*)(p + (size_t)n * O_);   // coalesced 64B/node
            pout[0] = make_float4(pv[0],  pv[1],  pv[2],  pv[3]);
            pout[1] = make_float4(pv[4],  pv[5],  pv[6],  pv[7]);
            pout[2] = make_float4(pv[8],  pv[9],  pv[10], pv[11]);
            pout[3] = make_float4(pv[12], pv[13], pv[14], pv[15]);
        }
    } else {
        const int j0 = (blk - PROJ_BLKS) * 256 + tid;
        for (int n = j0; n < NODES; n += BIN_BLKS * 256) {
            const int b = n / K_;                       // const-div -> magic mul
            const int local = n - b * K_;               // 17 bits
            int xs, ys; decode_xy(xy, fp32, n, xs, ys);
            const int t = (types[n] != 0);
            const int xlo = max((xs - 1) >> 5, 0), xhi = min((xs + 1) >> 5, NTX - 1);
            const int ylo = max((ys - 1) >> 4, 0), yhi = min((ys + 1) >> 4, NTY - 1);
            for (int tyy = ylo; tyy <= yhi; ++tyy)
                for (int txx = xlo; txx <= xhi; ++txx) {
                    const int bkg = (b * NTY + tyy) * NTX + txx;
                    const int slot = atomicAdd(&cursor[bkg * CURP], 1);
                    if (slot < CAP) {
                        const int lx = xs - (txx << 5) + 1;   // [0,33] 6 bits
                        const int ly = ys - (tyy << 4) + 1;   // [0,17] 5 bits
                        ids[bkg * CAP + slot] =
                            local | (t << 17) | (lx << 18) | (ly << 24);
                    }
                }
        }
    }
}

// ---------------------------------------------------------------------------
// Pass 2 (fused): per 32x16 tile — the round-4 champion (96.1 us), verbatim.
// NT stores; unconditional ids load (parallel with cursor load); wave-spread
// node mapping; zero-fill covers the gather latency.
// ---------------------------------------------------------------------------
template<bool PRE>
__global__ __launch_bounds__(512) void tile_fused(
    const void* __restrict__ src /* p if PRE else feat */,
    const void* __restrict__ xy,
    const void* __restrict__ w_obj, const void* __restrict__ w_prior,
    const int* __restrict__ cursor, const int* __restrict__ ids,
    void* __restrict__ out)
{
    __shared__ float accs[O_ * PLANE];               // 39,168 B -> 4 blocks/CU
    __shared__ float wl[PRE ? 2 : 2 * O_ * C_];

    const int tid = threadIdx.x;
    const int tx = blockIdx.x, ty = blockIdx.y, b = blockIdx.z;
    const int bucket = (b * NTY + ty) * NTX + tx;
    int cnt = cursor[bucket * CURP];
    if (cnt > CAP) cnt = CAP;
    const int fp32 = probe_fp32_ballot((const unsigned int*)xy);

    const int node = ((tid & 7) << 6) | (tid >> 3);  // bijective wave-spread
    const unsigned pck = (unsigned)ids[bucket * CAP + node];  // uncond issue
    const int local = pck & 0x1FFFF;
    const int t  = (pck >> 17) & 1;
    const int lx = (pck >> 18) & 63;
    const int ly = (pck >> 24) & 31;
    const bool active = (node < cnt);

    float f[16];
    if (active) {
        const size_t n = (size_t)b * K_ + local;
        if constexpr (PRE) {
            const float4* pp = (const float4*)src + n * 4;
            float4 a = pp[0], b2 = pp[1], c = pp[2], d = pp[3];
            f[0]=a.x; f[1]=a.y; f[2]=a.z; f[3]=a.w;
            f[4]=b2.x; f[5]=b2.y; f[6]=b2.z; f[7]=b2.w;
            f[8]=c.x; f[9]=c.y; f[10]=c.z; f[11]=c.w;
            f[12]=d.x; f[13]=d.y; f[14]=d.z; f[15]=d.w;
        } else {
            load_feat16(src, n, fp32, f);
        }
    }

    for (int i = tid; i < O_ * PLANE; i += 512) accs[i] = 0.f;
    if constexpr (!PRE) load_weights_lds(wl, fp32, w_obj, w_prior, tid, 512);
    __syncthreads();

    if (active) {
        float* cell = &accs[ly * EX + lx];
        if constexpr (PRE) {
            #pragma unroll
            for (int o = 0; o < O_; ++o) atomicAdd(cell + o * PLANE, f[o]);
        } else {
            const float* wrow = &wl[t * O_ * C_];
            #pragma unroll
            for (int o = 0; o < O_; ++o) {
                float acc = 0.f;
                #pragma unroll
                for (int c = 0; c < C_; ++c) acc = fmaf(wrow[o * C_ + c], f[c], acc);
                atomicAdd(cell + o * PLANE, acc);
            }
        }
    }
    __syncthreads();

    // conv: thread = (o = tid>>5, x = tid&31); rolling vertical window.
    const int x = tid & 31;
    const int o = tid >> 5;
    const float* pl = &accs[o * PLANE + x];
    float hA2 = 0.f, hA1 = 0.f, hB1 = 0.f;
    const int x0 = tx * TSX, y0 = ty * TSY;
    const size_t obase = (((size_t)(b * O_ + o)) * H_) * W_;

    #pragma unroll
    for (int iy = 0; iy < EY; ++iy) {
        float l = pl[iy * EX], c = pl[iy * EX + 1], r = pl[iy * EX + 2];
        float sfx = l + r;
        float hA = fmaf(0.075f, sfx, 0.125f * c);
        float hB = fmaf(0.125f, sfx, 0.3f * c);
        if (iy >= 2) {
            float v = hA2 + hB1 + hA;
            size_t oi = obase + (size_t)(y0 + iy - 2) * W_ + (x0 + x);
            if (fp32) __builtin_nontemporal_store(v, (float*)out + oi);
            else      __builtin_nontemporal_store(f2bf(v), (unsigned short*)out + oi);
        }
        hA2 = hA1; hA1 = hA; hB1 = hB;
    }
}

extern "C" void kernel_launch(void* const* d_in, const int* in_sizes, int n_in,
                              void* d_out, int out_size, void* d_ws, size_t ws_size,
                              hipStream_t stream)
{
    const void* feat = d_in[0];                    // [8,100000,16] fp32 (or bf16)
    const void* xy = d_in[1];                      // [8,100000,2]
    // d_in[2] = hw (int64 [2]) -- constants 512x512, unused
    const int* types = (const int*)d_in[3];        // int32 [8,100000]
    const void* w_obj = d_in[4];                   // [16,16]
    const void* w_prior = d_in[5];                 // [16,16]

    int* cursor = (int*)d_ws;                      // padded: one 64B line each
    int* ids = (int*)((char*)d_ws + IDS_OFF);
    float* p = (float*)((char*)d_ws + P_OFF);

    hipMemsetAsync(cursor, 0, CUR_BYTES, stream);
    if (ws_size >= WS_NEED_PRE) {
        proj_bin<true><<<TOTAL_BLKS, 256, 0, stream>>>(
            feat, xy, types, w_obj, w_prior, cursor, ids, p);
        tile_fused<true><<<dim3(NTX, NTY, B_), 512, 0, stream>>>(
            p, xy, w_obj, w_prior, cursor, ids, d_out);
    } else {
        proj_bin<false><<<TOTAL_BLKS, 256, 0, stream>>>(
            feat, xy, types, w_obj, w_prior, cursor, ids, p);
        tile_fused<false><<<dim3(NTX, NTY, B_), 512, 0, stream>>>(
            feat, xy, w_obj, w_prior, cursor, ids, d_out);
    }
}